// Round 13
// baseline (124.925 us; speedup 1.0000x reference)
//
#include <hip/hip_runtime.h>
#include <hip/hip_bf16.h>
#include <math.h>

constexpr int D = 256;
constexpr int N = 32768;    // 32 * 32 * 32
constexpr int K = 1024;
constexpr float MARGIN = 4e-4f;   // ~14 sigma of bf16-approx dist error (sigma~2.9e-5)

constexpr int OFF_Q    = 0;
constexpr int OFF_LOSS = 8388608;
constexpr int OFF_PERP = 8388609;
constexpr int OFF_IDX  = 8388610;
constexpr int OFF_DIST = 8421378;  // 8B-aligned only

using f32x4 = __attribute__((ext_vector_type(4))) float;
using s16x8 = __attribute__((ext_vector_type(8))) short;
using u16x8 = __attribute__((ext_vector_type(8))) unsigned short;
using u16x4 = __attribute__((ext_vector_type(4))) unsigned short;

#define GLOAD_LDS16(g, l)                                                     \
    __builtin_amdgcn_global_load_lds(                                         \
        (const __attribute__((address_space(1))) void*)(g),                   \
        (__attribute__((address_space(3))) void*)(l), 16, 0, 0)

__device__ __forceinline__ unsigned short bf16_bits(float v) {
    __hip_bfloat16 h = __float2bfloat16(v);
    return *(unsigned short*)&h;
}

// ---- split_z (y<32): z -> A(bf16), znorm.  (y==32): codebook prep ----
__global__ __launch_bounds__(256) void split_z_kernel(const float* __restrict__ z,
                                                      const float* __restrict__ cb,
                                                      unsigned short* __restrict__ A,
                                                      float* __restrict__ znorm,
                                                      unsigned short* __restrict__ Bb,
                                                      float* __restrict__ cnorm,
                                                      int* __restrict__ hist) {
    int t = threadIdx.x;
    if (blockIdx.y == 32) {
        int gid = blockIdx.x * 256 + t;
        if (gid < K) hist[gid] = 0;
        int lane = t & 63, wv = t >> 6;
        #pragma unroll 4
        for (int i = 0; i < 16; ++i) {
            int k = blockIdx.x * 64 + wv * 16 + i;
            float4 v = *(const float4*)(cb + (size_t)k * D + lane * 4);
            unsigned short hb[4] = {bf16_bits(v.x), bf16_bits(v.y),
                                    bf16_bits(v.z), bf16_bits(v.w)};
            *(u16x4*)(Bb + (size_t)k * D + lane * 4) = *(u16x4*)&hb[0];
            float s = v.x * v.x + v.y * v.y + v.z * v.z + v.w * v.w;
            #pragma unroll
            for (int off = 32; off; off >>= 1) s += __shfl_down(s, off, 64);
            if (lane == 0) cnorm[k] = s;
        }
        return;
    }

    __shared__ float tile[64][65];
    __shared__ float znp[64][4];
    int r0 = blockIdx.x * 64;
    int b  = blockIdx.y;
    const float* zb = z + (size_t)b * D * 1024;
    int rr4 = (t & 15) * 4;
    int rr = t >> 2, chunk = t & 3;
    size_t n = (size_t)b * 1024 + r0 + rr;
    float zacc = 0.f;

    for (int dblk = 0; dblk < 4; ++dblk) {
        int d0 = dblk * 64;
        if (dblk) __syncthreads();
        #pragma unroll
        for (int i = 0; i < 4; ++i) {
            int di = i * 16 + (t >> 4);
            float4 v = *(const float4*)(zb + (size_t)(d0 + di) * 1024 + r0 + rr4);
            *(float4*)&tile[di][rr4] = v;
        }
        __syncthreads();

        unsigned short hbuf[16];
        #pragma unroll
        for (int i = 0; i < 16; ++i) {
            float v = tile[chunk * 16 + i][rr];
            hbuf[i] = bf16_bits(v);
            zacc += v * v;
        }
        unsigned short* pa = A + n * 256 + d0 + chunk * 16;
        *(u16x8*)(pa + 0) = *(u16x8*)&hbuf[0];
        *(u16x8*)(pa + 8) = *(u16x8*)&hbuf[8];
    }
    znp[rr][chunk] = zacc;
    __syncthreads();
    if (t < 64) {
        float s = znp[t][0] + znp[t][1] + znp[t][2] + znp[t][3];
        znorm[(size_t)b * 1024 + r0 + t] = s;
    }
}

// ---- approx distance GEMM + fused per-64col argmin partials (XCD-swizzled) ----
// dist stores are NONTEMPORAL: write-only stream, keep L2 for the A panel.
__global__ __launch_bounds__(256) void dist_gemm_mfma(const unsigned short* __restrict__ A,
                                                      const unsigned short* __restrict__ Bb,
                                                      const float* __restrict__ znorm,
                                                      const float* __restrict__ cnorm,
                                                      float* __restrict__ dist,
                                                      float* __restrict__ pmin,
                                                      unsigned long long* __restrict__ pmask) {
    __shared__ unsigned short As[128 * 64];
    __shared__ unsigned short Bs[128 * 64];

    int t = threadIdx.x;
    int l = t & 63;
    int w = t >> 6;
    int p = blockIdx.x;
    int xcd = p & 7, j = p >> 3;
    int nb = xcd * 32 + (j >> 3);
    int kbl = j & 7;
    int k0 = kbl * 128;
    int n0 = nb * 128;

    int srow = t >> 3;
    int scol = (t & 7) * 8;
    const unsigned short* Ab = A + ((size_t)(n0 + srow)) * 256 + scol;
    const unsigned short* Bbp = Bb + ((size_t)(k0 + srow)) * 256 + scol;
    unsigned short* AsBase = As + t * 8;
    unsigned short* BsBase = Bs + t * 8;

    f32x4 acc[4][4];
    #pragma unroll
    for (int i = 0; i < 4; ++i)
        #pragma unroll
        for (int jj = 0; jj < 4; ++jj) acc[i][jj] = (f32x4){0.f, 0.f, 0.f, 0.f};

    int wr = w >> 1, wc = w & 1;
    int aRowBase = wr * 64 + (l & 15);
    int bRowBase = wc * 64 + (l & 15);
    int kLane = (l >> 4) * 8;

    #pragma unroll
    for (int kt = 0; kt < 4; ++kt) {
        int col = kt * 64;
        #pragma unroll
        for (int pass = 0; pass < 4; ++pass) {
            GLOAD_LDS16(Ab + (size_t)pass * 32 * 256 + col, AsBase + pass * 2048);
            GLOAD_LDS16(Bbp + (size_t)pass * 32 * 256 + col, BsBase + pass * 2048);
        }
        __syncthreads();

        #pragma unroll
        for (int kk = 0; kk < 64; kk += 32) {
            s16x8 af[4], bf[4];
            #pragma unroll
            for (int mf = 0; mf < 4; ++mf)
                af[mf] = *(const s16x8*)&As[(aRowBase + mf * 16) * 64 + kk + kLane];
            #pragma unroll
            for (int nf = 0; nf < 4; ++nf)
                bf[nf] = *(const s16x8*)&Bs[(bRowBase + nf * 16) * 64 + kk + kLane];
            #pragma unroll
            for (int mf = 0; mf < 4; ++mf)
                #pragma unroll
                for (int nf = 0; nf < 4; ++nf)
                    acc[mf][nf] = __builtin_amdgcn_mfma_f32_16x16x32_bf16(
                        af[mf], bf[nf], acc[mf][nf], 0, 0, 0);
        }
        if (kt < 3) __syncthreads();
    }

    int colBase = k0 + wc * 64 + (l & 15);
    int rowBase = n0 + wr * 64 + (l >> 4) * 4;
    int kb = kbl * 2 + wc;
    int g = l >> 4;
    float cn[4];
    #pragma unroll
    for (int nf = 0; nf < 4; ++nf) cn[nf] = cnorm[colBase + nf * 16];
    #pragma unroll
    for (int mf = 0; mf < 4; ++mf) {
        #pragma unroll
        for (int r = 0; r < 4; ++r) {
            int n = rowBase + mf * 16 + r;
            float zn = znorm[n];
            float* pr = dist + (size_t)n * K;
            float dv[4];
            #pragma unroll
            for (int nf = 0; nf < 4; ++nf) {
                dv[nf] = zn + cn[nf] - 2.0f * acc[mf][nf][r];
                __builtin_nontemporal_store(dv[nf], &pr[colBase + nf * 16]);
            }
            float m4 = fminf(fminf(dv[0], dv[1]), fminf(dv[2], dv[3]));
            #pragma unroll
            for (int off = 1; off < 16; off <<= 1)
                m4 = fminf(m4, __shfl_xor(m4, off, 64));
            float th = m4 + MARGIN;
            unsigned long long bal[4];
            #pragma unroll
            for (int nf = 0; nf < 4; ++nf)
                bal[nf] = __ballot(dv[nf] <= th);
            if ((l & 15) == 0) {
                unsigned long long msk = 0;
                #pragma unroll
                for (int nf = 0; nf < 4; ++nf)
                    msk |= ((bal[nf] >> (g * 16)) & 0xFFFFULL) << (nf * 16);
                pmin[(size_t)n * 16 + kb] = m4;
                pmask[(size_t)n * 16 + kb] = msk;
            }
        }
    }
}

// ---- resolve: WAVE per row; slow path reads z directly (L3-resident) ----
__global__ __launch_bounds__(256) void resolve_kernel(const float* __restrict__ pmin,
                                                      const unsigned long long* __restrict__ pmask,
                                                      const float* __restrict__ z,
                                                      const float* __restrict__ cb,
                                                      const float* __restrict__ znorm,
                                                      const float* __restrict__ cnorm,
                                                      int* __restrict__ idx_i,
                                                      float* __restrict__ out_idx,
                                                      int* __restrict__ hist,
                                                      float* __restrict__ mse_part) {
    __shared__ float s4[4];
    int n = blockIdx.x * 4 + (threadIdx.x >> 6);
    int lane = threadIdx.x & 63;
    int s16 = lane & 15;

    float myp = pmin[(size_t)n * 16 + s16];
    float gmin = myp;
    #pragma unroll
    for (int off = 1; off < 16; off <<= 1)
        gmin = fminf(gmin, __shfl_xor(gmin, off, 64));
    float th = gmin + MARGIN;

    unsigned long long mym = (myp <= th) ? pmask[(size_t)n * 16 + s16] : 0ULL;
    int total = __popcll(mym);
    #pragma unroll
    for (int off = 1; off < 16; off <<= 1)
        total += __shfl_xor(total, off, 64);

    int besti;
    if (total == 1) {
        int cand = mym ? (s16 * 64 + __builtin_ctzll(mym)) : 0x7fffffff;
        #pragma unroll
        for (int off = 1; off < 16; off <<= 1)
            cand = min(cand, __shfl_xor(cand, off, 64));
        besti = cand;
    } else {
        // exact fp32 on the same coarse grid as the reference (keep +zn!)
        int b = n >> 10, r = n & 1023;
        const float* zb = z + (size_t)b * D * 1024 + r;
        float zv[4];
        #pragma unroll
        for (int q = 0; q < 4; ++q)
            zv[q] = zb[(size_t)(lane + 64 * q) * 1024];
        float zn = znorm[n];
        float bestv = INFINITY;
        besti = 0x7fffffff;
        for (int kb = 0; kb < 16; ++kb) {
            unsigned long long m = __shfl(mym, kb, 64);
            while (m) {
                int lb = __builtin_ctzll(m);
                m &= m - 1;
                int k = kb * 64 + lb;
                const float* cr = cb + (size_t)k * D + lane;
                float s = zv[0] * cr[0] + zv[1] * cr[64] + zv[2] * cr[128] + zv[3] * cr[192];
                #pragma unroll
                for (int off = 1; off < 64; off <<= 1)
                    s += __shfl_xor(s, off, 64);
                float dd = zn + cnorm[k] - 2.0f * s;
                if (dd < bestv) { bestv = dd; besti = k; }
            }
        }
    }

    if (lane == 0) {
        idx_i[n] = besti;
        out_idx[n] = (float)besti;
        atomicAdd(&hist[besti], 1);
        s4[threadIdx.x >> 6] = gmin;
    }
    __syncthreads();
    if (threadIdx.x == 0)
        mse_part[blockIdx.x] = (s4[0] + s4[1]) + (s4[2] + s4[3]);
}

// ---- gather: out_q = cb[idx] (pure write); block (0,0) also finalizes ----
__global__ __launch_bounds__(256) void gather_kernel(const float* __restrict__ cb,
                                                     const int* __restrict__ idx_i,
                                                     float* __restrict__ out_q,
                                                     const float* __restrict__ mse_part,
                                                     const int* __restrict__ hist,
                                                     float* __restrict__ out) {
    int t = threadIdx.x;
    int n = blockIdx.x * 256 + t;
    int b = n >> 10, r = n & 1023;
    float* qp = out_q + (size_t)b * D * 1024 + r;
    const float* crow = cb + (size_t)idx_i[n] * D;
    int c0 = blockIdx.y * 32;

    #pragma unroll
    for (int c = 0; c < 32; c += 4) {
        float4 v = *(const float4*)(crow + c0 + c);
        qp[(size_t)(c0 + c + 0) * 1024] = v.x;
        qp[(size_t)(c0 + c + 1) * 1024] = v.y;
        qp[(size_t)(c0 + c + 2) * 1024] = v.z;
        qp[(size_t)(c0 + c + 3) * 1024] = v.w;
    }

    if (blockIdx.x == 0 && blockIdx.y == 0) {
        __shared__ float red[256];
        float s = 0.f;
        for (int i = t; i < 8192; i += 256) s += mse_part[i];
        red[t] = s;
        __syncthreads();
        #pragma unroll
        for (int off = 128; off; off >>= 1) {
            if (t < off) red[t] += red[t + off];
            __syncthreads();
        }
        float msesum = red[0];
        __syncthreads();
        float e = 0.f;
        for (int k = t; k < K; k += 256) {
            float p = (float)hist[k] * (1.0f / (float)N);
            e += p * logf(p + 1e-10f);
        }
        red[t] = e;
        __syncthreads();
        #pragma unroll
        for (int off = 128; off; off >>= 1) {
            if (t < off) red[t] += red[t + off];
            __syncthreads();
        }
        if (t == 0) {
            float mse = msesum / (float)((size_t)N * D);
            out[OFF_LOSS] = 1.25f * mse;
            out[OFF_PERP] = expf(-red[0]);
        }
    }
}

extern "C" void kernel_launch(void* const* d_in, const int* in_sizes, int n_in,
                              void* d_out, int out_size, void* d_ws, size_t ws_size,
                              hipStream_t stream) {
    const float* z  = (const float*)d_in[0];
    const float* cb = (const float*)d_in[1];
    float* out = (float*)d_out;

    char* wsb = (char*)d_ws;
    size_t off = 0;
    unsigned short* A  = (unsigned short*)(wsb + off); off += (size_t)N * 256 * 2;   // 16.78 MB
    unsigned short* Bb = (unsigned short*)(wsb + off); off += (size_t)K * 256 * 2;   // 0.52 MB
    float* pmin        = (float*)(wsb + off);          off += (size_t)N * 16 * 4;    // 2.10 MB
    unsigned long long* pmask = (unsigned long long*)(wsb + off); off += (size_t)N * 16 * 8; // 4.19 MB
    float* znorm       = (float*)(wsb + off);          off += (size_t)N * 4;
    float* cnorm       = (float*)(wsb + off);          off += (size_t)K * 4;
    float* mse_part    = (float*)(wsb + off);          off += 8192 * 4;
    int* hist          = (int*)(wsb + off);            off += (size_t)K * 4;
    int* idx_i         = (int*)(wsb + off);

    split_z_kernel<<<dim3(16, 33), 256, 0, stream>>>(z, cb, A, znorm, Bb, cnorm, hist);
    dist_gemm_mfma<<<2048, 256, 0, stream>>>(A, Bb, znorm, cnorm,
                                             out + OFF_DIST, pmin, pmask);
    resolve_kernel<<<N / 4, 256, 0, stream>>>(pmin, pmask, z, cb, znorm, cnorm,
                                              idx_i, out + OFF_IDX, hist, mse_part);
    gather_kernel<<<dim3(128, 8), 256, 0, stream>>>(cb, idx_i, out + OFF_Q,
                                                    mse_part, hist, out);
}

// Round 14
// 102.329 us; speedup vs baseline: 1.2208x; 1.2208x over previous
//
#include <hip/hip_runtime.h>
#include <hip/hip_bf16.h>
#include <math.h>

constexpr int D = 256;
constexpr int N = 32768;    // 32 * 32 * 32
constexpr int K = 1024;
constexpr float MARGIN = 4e-4f;   // ~14 sigma of bf16-approx dist error (sigma~2.9e-5)

constexpr int OFF_Q    = 0;
constexpr int OFF_LOSS = 8388608;
constexpr int OFF_PERP = 8388609;
constexpr int OFF_IDX  = 8388610;
constexpr int OFF_DIST = 8421378;  // 8B-aligned only

using f32x4 = __attribute__((ext_vector_type(4))) float;
using s16x8 = __attribute__((ext_vector_type(8))) short;
using u16x8 = __attribute__((ext_vector_type(8))) unsigned short;
using u16x4 = __attribute__((ext_vector_type(4))) unsigned short;

#define GLOAD_LDS16(g, l)                                                     \
    __builtin_amdgcn_global_load_lds(                                         \
        (const __attribute__((address_space(1))) void*)(g),                   \
        (__attribute__((address_space(3))) void*)(l), 16, 0, 0)

__device__ __forceinline__ unsigned short bf16_bits(float v) {
    __hip_bfloat16 h = __float2bfloat16(v);
    return *(unsigned short*)&h;
}

// ---- split_z (y<32): z -> A(bf16), znorm.  (y==32): codebook prep ----
__global__ __launch_bounds__(256) void split_z_kernel(const float* __restrict__ z,
                                                      const float* __restrict__ cb,
                                                      unsigned short* __restrict__ A,
                                                      float* __restrict__ znorm,
                                                      unsigned short* __restrict__ Bb,
                                                      float* __restrict__ cnorm,
                                                      int* __restrict__ hist) {
    int t = threadIdx.x;
    if (blockIdx.y == 32) {
        int gid = blockIdx.x * 256 + t;
        if (gid < K) hist[gid] = 0;
        int lane = t & 63, wv = t >> 6;
        #pragma unroll 4
        for (int i = 0; i < 16; ++i) {
            int k = blockIdx.x * 64 + wv * 16 + i;
            float4 v = *(const float4*)(cb + (size_t)k * D + lane * 4);
            unsigned short hb[4] = {bf16_bits(v.x), bf16_bits(v.y),
                                    bf16_bits(v.z), bf16_bits(v.w)};
            *(u16x4*)(Bb + (size_t)k * D + lane * 4) = *(u16x4*)&hb[0];
            float s = v.x * v.x + v.y * v.y + v.z * v.z + v.w * v.w;
            #pragma unroll
            for (int off = 32; off; off >>= 1) s += __shfl_down(s, off, 64);
            if (lane == 0) cnorm[k] = s;
        }
        return;
    }

    __shared__ float tile[64][65];
    __shared__ float znp[64][4];
    int r0 = blockIdx.x * 64;
    int b  = blockIdx.y;
    const float* zb = z + (size_t)b * D * 1024;
    int rr4 = (t & 15) * 4;
    int rr = t >> 2, chunk = t & 3;
    size_t n = (size_t)b * 1024 + r0 + rr;
    float zacc = 0.f;

    for (int dblk = 0; dblk < 4; ++dblk) {
        int d0 = dblk * 64;
        if (dblk) __syncthreads();
        #pragma unroll
        for (int i = 0; i < 4; ++i) {
            int di = i * 16 + (t >> 4);
            float4 v = *(const float4*)(zb + (size_t)(d0 + di) * 1024 + r0 + rr4);
            *(float4*)&tile[di][rr4] = v;
        }
        __syncthreads();

        unsigned short hbuf[16];
        #pragma unroll
        for (int i = 0; i < 16; ++i) {
            float v = tile[chunk * 16 + i][rr];
            hbuf[i] = bf16_bits(v);
            zacc += v * v;
        }
        unsigned short* pa = A + n * 256 + d0 + chunk * 16;
        *(u16x8*)(pa + 0) = *(u16x8*)&hbuf[0];
        *(u16x8*)(pa + 8) = *(u16x8*)&hbuf[8];
    }
    znp[rr][chunk] = zacc;
    __syncthreads();
    if (t < 64) {
        float s = znp[t][0] + znp[t][1] + znp[t][2] + znp[t][3];
        znorm[(size_t)b * 1024 + r0 + t] = s;
    }
}

// ---- approx distance GEMM + fused per-64col argmin partials (XCD-swizzled) ----
__global__ __launch_bounds__(256) void dist_gemm_mfma(const unsigned short* __restrict__ A,
                                                      const unsigned short* __restrict__ Bb,
                                                      const float* __restrict__ znorm,
                                                      const float* __restrict__ cnorm,
                                                      float* __restrict__ dist,
                                                      float* __restrict__ pmin,
                                                      unsigned long long* __restrict__ pmask) {
    __shared__ unsigned short As[128 * 64];
    __shared__ unsigned short Bs[128 * 64];

    int t = threadIdx.x;
    int l = t & 63;
    int w = t >> 6;
    int p = blockIdx.x;
    int xcd = p & 7, j = p >> 3;
    int nb = xcd * 32 + (j >> 3);
    int kbl = j & 7;
    int k0 = kbl * 128;
    int n0 = nb * 128;

    int srow = t >> 3;
    int scol = (t & 7) * 8;
    const unsigned short* Ab = A + ((size_t)(n0 + srow)) * 256 + scol;
    const unsigned short* Bbp = Bb + ((size_t)(k0 + srow)) * 256 + scol;
    unsigned short* AsBase = As + t * 8;
    unsigned short* BsBase = Bs + t * 8;

    f32x4 acc[4][4];
    #pragma unroll
    for (int i = 0; i < 4; ++i)
        #pragma unroll
        for (int jj = 0; jj < 4; ++jj) acc[i][jj] = (f32x4){0.f, 0.f, 0.f, 0.f};

    int wr = w >> 1, wc = w & 1;
    int aRowBase = wr * 64 + (l & 15);
    int bRowBase = wc * 64 + (l & 15);
    int kLane = (l >> 4) * 8;

    #pragma unroll
    for (int kt = 0; kt < 4; ++kt) {
        int col = kt * 64;
        #pragma unroll
        for (int pass = 0; pass < 4; ++pass) {
            GLOAD_LDS16(Ab + (size_t)pass * 32 * 256 + col, AsBase + pass * 2048);
            GLOAD_LDS16(Bbp + (size_t)pass * 32 * 256 + col, BsBase + pass * 2048);
        }
        __syncthreads();

        #pragma unroll
        for (int kk = 0; kk < 64; kk += 32) {
            s16x8 af[4], bf[4];
            #pragma unroll
            for (int mf = 0; mf < 4; ++mf)
                af[mf] = *(const s16x8*)&As[(aRowBase + mf * 16) * 64 + kk + kLane];
            #pragma unroll
            for (int nf = 0; nf < 4; ++nf)
                bf[nf] = *(const s16x8*)&Bs[(bRowBase + nf * 16) * 64 + kk + kLane];
            #pragma unroll
            for (int mf = 0; mf < 4; ++mf)
                #pragma unroll
                for (int nf = 0; nf < 4; ++nf)
                    acc[mf][nf] = __builtin_amdgcn_mfma_f32_16x16x32_bf16(
                        af[mf], bf[nf], acc[mf][nf], 0, 0, 0);
        }
        if (kt < 3) __syncthreads();
    }

    int colBase = k0 + wc * 64 + (l & 15);
    int rowBase = n0 + wr * 64 + (l >> 4) * 4;
    int kb = kbl * 2 + wc;
    int g = l >> 4;
    float cn[4];
    #pragma unroll
    for (int nf = 0; nf < 4; ++nf) cn[nf] = cnorm[colBase + nf * 16];
    #pragma unroll
    for (int mf = 0; mf < 4; ++mf) {
        #pragma unroll
        for (int r = 0; r < 4; ++r) {
            int n = rowBase + mf * 16 + r;
            float zn = znorm[n];
            float* pr = dist + (size_t)n * K;
            float dv[4];
            #pragma unroll
            for (int nf = 0; nf < 4; ++nf) {
                dv[nf] = zn + cn[nf] - 2.0f * acc[mf][nf][r];
                pr[colBase + nf * 16] = dv[nf];
            }
            float m4 = fminf(fminf(dv[0], dv[1]), fminf(dv[2], dv[3]));
            #pragma unroll
            for (int off = 1; off < 16; off <<= 1)
                m4 = fminf(m4, __shfl_xor(m4, off, 64));
            float th = m4 + MARGIN;
            unsigned long long bal[4];
            #pragma unroll
            for (int nf = 0; nf < 4; ++nf)
                bal[nf] = __ballot(dv[nf] <= th);
            if ((l & 15) == 0) {
                unsigned long long msk = 0;
                #pragma unroll
                for (int nf = 0; nf < 4; ++nf)
                    msk |= ((bal[nf] >> (g * 16)) & 0xFFFFULL) << (nf * 16);
                pmin[(size_t)n * 16 + kb] = m4;
                pmask[(size_t)n * 16 + kb] = msk;
            }
        }
    }
}

// ---- resolve: WAVE per row; slow path reads z directly (L3-resident) ----
__global__ __launch_bounds__(256) void resolve_kernel(const float* __restrict__ pmin,
                                                      const unsigned long long* __restrict__ pmask,
                                                      const float* __restrict__ z,
                                                      const float* __restrict__ cb,
                                                      const float* __restrict__ znorm,
                                                      const float* __restrict__ cnorm,
                                                      int* __restrict__ idx_i,
                                                      float* __restrict__ out_idx,
                                                      int* __restrict__ hist,
                                                      float* __restrict__ mse_part) {
    __shared__ float s4[4];
    int n = blockIdx.x * 4 + (threadIdx.x >> 6);
    int lane = threadIdx.x & 63;
    int s16 = lane & 15;

    float myp = pmin[(size_t)n * 16 + s16];
    float gmin = myp;
    #pragma unroll
    for (int off = 1; off < 16; off <<= 1)
        gmin = fminf(gmin, __shfl_xor(gmin, off, 64));
    float th = gmin + MARGIN;

    unsigned long long mym = (myp <= th) ? pmask[(size_t)n * 16 + s16] : 0ULL;
    int total = __popcll(mym);
    #pragma unroll
    for (int off = 1; off < 16; off <<= 1)
        total += __shfl_xor(total, off, 64);

    int besti;
    if (total == 1) {
        int cand = mym ? (s16 * 64 + __builtin_ctzll(mym)) : 0x7fffffff;
        #pragma unroll
        for (int off = 1; off < 16; off <<= 1)
            cand = min(cand, __shfl_xor(cand, off, 64));
        besti = cand;
    } else {
        // exact fp32 on the same coarse grid as the reference (keep +zn!)
        int b = n >> 10, r = n & 1023;
        const float* zb = z + (size_t)b * D * 1024 + r;
        float zv[4];
        #pragma unroll
        for (int q = 0; q < 4; ++q)
            zv[q] = zb[(size_t)(lane + 64 * q) * 1024];
        float zn = znorm[n];
        float bestv = INFINITY;
        besti = 0x7fffffff;
        for (int kb = 0; kb < 16; ++kb) {
            unsigned long long m = __shfl(mym, kb, 64);
            while (m) {
                int lb = __builtin_ctzll(m);
                m &= m - 1;
                int k = kb * 64 + lb;
                const float* cr = cb + (size_t)k * D + lane;
                float s = zv[0] * cr[0] + zv[1] * cr[64] + zv[2] * cr[128] + zv[3] * cr[192];
                #pragma unroll
                for (int off = 1; off < 64; off <<= 1)
                    s += __shfl_xor(s, off, 64);
                float dd = zn + cnorm[k] - 2.0f * s;
                if (dd < bestv) { bestv = dd; besti = k; }
            }
        }
    }

    if (lane == 0) {
        idx_i[n] = besti;
        out_idx[n] = (float)besti;
        atomicAdd(&hist[besti], 1);
        s4[threadIdx.x >> 6] = gmin;
    }
    __syncthreads();
    if (threadIdx.x == 0)
        mse_part[blockIdx.x] = (s4[0] + s4[1]) + (s4[2] + s4[3]);
}

// ---- gather: out_q = cb[idx] (pure write); block (0,0) also finalizes ----
__global__ __launch_bounds__(256) void gather_kernel(const float* __restrict__ cb,
                                                     const int* __restrict__ idx_i,
                                                     float* __restrict__ out_q,
                                                     const float* __restrict__ mse_part,
                                                     const int* __restrict__ hist,
                                                     float* __restrict__ out) {
    int t = threadIdx.x;
    int n = blockIdx.x * 256 + t;
    int b = n >> 10, r = n & 1023;
    float* qp = out_q + (size_t)b * D * 1024 + r;
    const float* crow = cb + (size_t)idx_i[n] * D;
    int c0 = blockIdx.y * 32;

    #pragma unroll
    for (int c = 0; c < 32; c += 4) {
        float4 v = *(const float4*)(crow + c0 + c);
        qp[(size_t)(c0 + c + 0) * 1024] = v.x;
        qp[(size_t)(c0 + c + 1) * 1024] = v.y;
        qp[(size_t)(c0 + c + 2) * 1024] = v.z;
        qp[(size_t)(c0 + c + 3) * 1024] = v.w;
    }

    if (blockIdx.x == 0 && blockIdx.y == 0) {
        __shared__ float red[256];
        float s = 0.f;
        for (int i = t; i < 8192; i += 256) s += mse_part[i];
        red[t] = s;
        __syncthreads();
        #pragma unroll
        for (int off = 128; off; off >>= 1) {
            if (t < off) red[t] += red[t + off];
            __syncthreads();
        }
        float msesum = red[0];
        __syncthreads();
        float e = 0.f;
        for (int k = t; k < K; k += 256) {
            float p = (float)hist[k] * (1.0f / (float)N);
            e += p * logf(p + 1e-10f);
        }
        red[t] = e;
        __syncthreads();
        #pragma unroll
        for (int off = 128; off; off >>= 1) {
            if (t < off) red[t] += red[t + off];
            __syncthreads();
        }
        if (t == 0) {
            float mse = msesum / (float)((size_t)N * D);
            out[OFF_LOSS] = 1.25f * mse;
            out[OFF_PERP] = expf(-red[0]);
        }
    }
}

extern "C" void kernel_launch(void* const* d_in, const int* in_sizes, int n_in,
                              void* d_out, int out_size, void* d_ws, size_t ws_size,
                              hipStream_t stream) {
    const float* z  = (const float*)d_in[0];
    const float* cb = (const float*)d_in[1];
    float* out = (float*)d_out;

    char* wsb = (char*)d_ws;
    size_t off = 0;
    unsigned short* A  = (unsigned short*)(wsb + off); off += (size_t)N * 256 * 2;   // 16.78 MB
    unsigned short* Bb = (unsigned short*)(wsb + off); off += (size_t)K * 256 * 2;   // 0.52 MB
    float* pmin        = (float*)(wsb + off);          off += (size_t)N * 16 * 4;    // 2.10 MB
    unsigned long long* pmask = (unsigned long long*)(wsb + off); off += (size_t)N * 16 * 8; // 4.19 MB
    float* znorm       = (float*)(wsb + off);          off += (size_t)N * 4;
    float* cnorm       = (float*)(wsb + off);          off += (size_t)K * 4;
    float* mse_part    = (float*)(wsb + off);          off += 8192 * 4;
    int* hist          = (int*)(wsb + off);            off += (size_t)K * 4;
    int* idx_i         = (int*)(wsb + off);

    split_z_kernel<<<dim3(16, 33), 256, 0, stream>>>(z, cb, A, znorm, Bb, cnorm, hist);
    dist_gemm_mfma<<<2048, 256, 0, stream>>>(A, Bb, znorm, cnorm,
                                             out + OFF_DIST, pmin, pmask);
    resolve_kernel<<<N / 4, 256, 0, stream>>>(pmin, pmask, z, cb, znorm, cnorm,
                                              idx_i, out + OFF_IDX, hist, mse_part);
    gather_kernel<<<dim3(128, 8), 256, 0, stream>>>(cb, idx_i, out + OFF_Q,
                                                    mse_part, hist, out);
}